// Round 5
// baseline (316.627 us; speedup 1.0000x reference)
//
#include <hip/hip_runtime.h>
#include <math.h>

#define NHEADS 8
#define KD 16
#define EMBED 128
#define BATCH 32
#define NSEQ 16384
#define NCHUNK 64
#define CHUNK (NSEQ / NCHUNK)   // 256 rows per chunk
#define PART_STRIDE 18          // m, l, acc[16]
#define PART_FLOATS (BATCH * NCHUNK * NHEADS * PART_STRIDE)

typedef float f32x2 __attribute__((ext_vector_type(2)));

// Fused kernel: per-(batch, chunk) online-softmax partials over all 8 heads;
// the last chunk-block of each batch (ticket via device-scope atomic) merges
// the 64 partials and applies the W_out projection. Eliminates the second
// kernel launch and overlaps merge with other batches' streaming.
__global__ __launch_bounds__(256) void attn_fused(
    const float* __restrict__ q,
    const float* __restrict__ K,
    const float* __restrict__ V,
    const float* __restrict__ mask,
    const float* __restrict__ Wout,
    float* __restrict__ out,
    float* __restrict__ part,
    unsigned int* __restrict__ cnt)
{
    const int b    = blockIdx.x >> 6;      // NCHUNK == 64
    const int c    = blockIdx.x & 63;
    const int wave = threadIdx.x >> 6;
    const int lane = threadIdx.x & 63;
    const int head = lane >> 3;
    const int g    = lane & 7;             // position within head group

    const f32x2 q2 = *(const f32x2*)&q[b * EMBED + 2 * lane];

    float m = -INFINITY;
    float lsum = 0.f;
    float accx = 0.f, accy = 0.f;

    const size_t rowbase = (size_t)b * NSEQ;
    const int r0 = c * CHUNK;

    #pragma unroll 4
    for (int r = r0 + wave; r < r0 + CHUNK; r += 4) {
        const size_t off = (rowbase + r) * EMBED + 2 * lane;
        const f32x2 k2 = __builtin_nontemporal_load((const f32x2*)&K[off]);
        const f32x2 v2 = __builtin_nontemporal_load((const f32x2*)&V[off]);
        float p = q2.x * k2.x + q2.y * k2.y;
        p += __shfl_xor(p, 1);
        p += __shfl_xor(p, 2);
        p += __shfl_xor(p, 4);
        const float s  = p * 0.25f + mask[rowbase + r];   // scale = 1/sqrt(16)
        const float mn = fmaxf(m, s);
        const float corr = __expf(m - mn);
        const float w    = __expf(s - mn);
        lsum = lsum * corr + w;
        accx = accx * corr + w * v2.x;
        accy = accy * corr + w * v2.y;
        m = mn;
    }

    // Combine the 4 waves' partials via LDS.
    __shared__ float lds[4][NHEADS][PART_STRIDE];
    __shared__ float heads[EMBED];
    __shared__ int last_flag;

    lds[wave][head][2 + 2 * g]     = accx;
    lds[wave][head][2 + 2 * g + 1] = accy;
    if (g == 0) {
        lds[wave][head][0] = m;
        lds[wave][head][1] = lsum;
    }
    __syncthreads();

    const int t = threadIdx.x;
    if (t < EMBED) {
        const int h = t >> 4;
        const int d = t & 15;
        float M = -INFINITY;
        #pragma unroll
        for (int w = 0; w < 4; ++w) M = fmaxf(M, lds[w][h][0]);
        float L = 0.f, A = 0.f;
        #pragma unroll
        for (int w = 0; w < 4; ++w) {
            const float e = __expf(lds[w][h][0] - M);
            L += lds[w][h][1] * e;
            A += lds[w][h][2 + d] * e;
        }
        float* p = &part[((size_t)(b * NCHUNK + c) * NHEADS + h) * PART_STRIDE];
        p[2 + d] = A;
        if (d == 0) { p[0] = M; p[1] = L; }
    }

    // Release: make this block's partial writes device-visible, then ticket.
    __threadfence();
    __syncthreads();
    if (t == 0) {
        const unsigned int old =
            __hip_atomic_fetch_add(&cnt[b], 1u, __ATOMIC_ACQ_REL,
                                   __HIP_MEMORY_SCOPE_AGENT);
        last_flag = (old == NCHUNK - 1);
    }
    __syncthreads();
    if (!last_flag) return;

    // Acquire: invalidate stale cache lines before reading other XCDs' parts.
    __threadfence();

    if (t < EMBED) {
        const int h = t >> 4;
        const int d = t & 15;
        float Mc[4], Lc[4], Ac[4];
        #pragma unroll
        for (int j = 0; j < 4; ++j) { Mc[j] = -INFINITY; Lc[j] = 0.f; Ac[j] = 0.f; }
        #pragma unroll 4
        for (int i = 0; i < 16; ++i) {
            #pragma unroll
            for (int j = 0; j < 4; ++j) {
                const int cc = j * 16 + i;
                const float* p = &part[((size_t)(b * NCHUNK + cc) * NHEADS + h) * PART_STRIDE];
                const float mc = p[0];
                const float lc = p[1];
                const float ac = p[2 + d];
                const float Mn = fmaxf(Mc[j], mc);
                const float eM = __expf(Mc[j] - Mn);
                const float ec = __expf(mc - Mn);
                Lc[j] = Lc[j] * eM + lc * ec;
                Ac[j] = Ac[j] * eM + ac * ec;
                Mc[j] = Mn;
            }
        }
        const float M = fmaxf(fmaxf(Mc[0], Mc[1]), fmaxf(Mc[2], Mc[3]));
        float L = 0.f, A = 0.f;
        #pragma unroll
        for (int j = 0; j < 4; ++j) {
            const float e = __expf(Mc[j] - M);
            L += Lc[j] * e;
            A += Ac[j] * e;
        }
        heads[t] = A / L;
    }
    __syncthreads();

    if (t < EMBED) {
        float o = 0.f;
        #pragma unroll 8
        for (int dd = 0; dd < EMBED; ++dd)
            o += heads[dd] * Wout[dd * EMBED + t];
        out[b * EMBED + t] = o;
    }
}

extern "C" void kernel_launch(void* const* d_in, const int* in_sizes, int n_in,
                              void* d_out, int out_size, void* d_ws, size_t ws_size,
                              hipStream_t stream) {
    const float* q    = (const float*)d_in[0];
    const float* K    = (const float*)d_in[1];
    const float* V    = (const float*)d_in[2];
    const float* mask = (const float*)d_in[3];
    const float* Wout = (const float*)d_in[4];
    float* out  = (float*)d_out;
    float* part = (float*)d_ws;                       // 1.18 MB of partials
    unsigned int* cnt = (unsigned int*)(part + PART_FLOATS);  // 32 tickets

    hipMemsetAsync(cnt, 0, BATCH * sizeof(unsigned int), stream);
    attn_fused<<<BATCH * NCHUNK, 256, 0, stream>>>(q, K, V, mask, Wout,
                                                   out, part, cnt);
}

// Round 6
// 87.683 us; speedup vs baseline: 3.6110x; 3.6110x over previous
//
#include <hip/hip_runtime.h>
#include <math.h>

#define NHEADS 8
#define KD 16
#define EMBED 128
#define BATCH 32
#define NSEQ 16384
#define NCHUNK 64
#define CHUNK (NSEQ / NCHUNK)   // 256 rows per chunk
#define PART_STRIDE 18          // m, l, acc[16]

typedef float f32x2 __attribute__((ext_vector_type(2)));

// Kernel 1 (identical to the proven 89.8us version): per-(batch, chunk)
// online-softmax partials over all 8 heads. Each wave reads whole 128-float
// rows: lane l covers dims [2l, 2l+1]; head = lane>>3. K/V are read-once
// streams -> nontemporal loads (no cache allocate).
__global__ __launch_bounds__(256) void attn_partial(
    const float* __restrict__ q,
    const float* __restrict__ K,
    const float* __restrict__ V,
    const float* __restrict__ mask,
    float* __restrict__ part)
{
    const int b    = blockIdx.x >> 6;      // NCHUNK == 64
    const int c    = blockIdx.x & 63;
    const int wave = threadIdx.x >> 6;
    const int lane = threadIdx.x & 63;
    const int head = lane >> 3;
    const int g    = lane & 7;             // position within head group

    const f32x2 q2 = *(const f32x2*)&q[b * EMBED + 2 * lane];

    float m = -INFINITY;
    float lsum = 0.f;
    float accx = 0.f, accy = 0.f;

    const size_t rowbase = (size_t)b * NSEQ;
    const int r0 = c * CHUNK;

    #pragma unroll 4
    for (int r = r0 + wave; r < r0 + CHUNK; r += 4) {
        const size_t off = (rowbase + r) * EMBED + 2 * lane;
        const f32x2 k2 = __builtin_nontemporal_load((const f32x2*)&K[off]);
        const f32x2 v2 = __builtin_nontemporal_load((const f32x2*)&V[off]);
        float p = q2.x * k2.x + q2.y * k2.y;
        p += __shfl_xor(p, 1);
        p += __shfl_xor(p, 2);
        p += __shfl_xor(p, 4);
        const float s  = p * 0.25f + mask[rowbase + r];   // scale = 1/sqrt(16)
        const float mn = fmaxf(m, s);
        const float corr = __expf(m - mn);
        const float w    = __expf(s - mn);
        lsum = lsum * corr + w;
        accx = accx * corr + w * v2.x;
        accy = accy * corr + w * v2.y;
        m = mn;
    }

    // Combine the 4 waves' partials via LDS.
    __shared__ float lds[4][NHEADS][PART_STRIDE];
    lds[wave][head][2 + 2 * g]     = accx;
    lds[wave][head][2 + 2 * g + 1] = accy;
    if (g == 0) {
        lds[wave][head][0] = m;
        lds[wave][head][1] = lsum;
    }
    __syncthreads();

    const int t = threadIdx.x;
    if (t < EMBED) {
        const int h = t >> 4;
        const int d = t & 15;
        float M = -INFINITY;
        #pragma unroll
        for (int w = 0; w < 4; ++w) M = fmaxf(M, lds[w][h][0]);
        float L = 0.f, A = 0.f;
        #pragma unroll
        for (int w = 0; w < 4; ++w) {
            const float e = __expf(lds[w][h][0] - M);
            L += lds[w][h][1] * e;
            A += lds[w][h][2 + d] * e;
        }
        float* p = &part[((size_t)(b * NCHUNK + c) * NHEADS + h) * PART_STRIDE];
        p[2 + d] = A;
        if (d == 0) { p[0] = M; p[1] = L; }
    }
}

// Kernel 2: merge chunk partials with 256 threads — two half-groups each
// merge 32 chunks in 4 independent chains of 8 (serial depth 16 -> 8),
// combine halves via LDS, normalize, apply W_out projection.
__global__ __launch_bounds__(256) void attn_finish(
    const float* __restrict__ part,
    const float* __restrict__ Wout,
    float* __restrict__ out)
{
    const int b    = blockIdx.x;
    const int t    = threadIdx.x;
    const int half = t >> 7;        // chunk range: half*32 .. half*32+31
    const int td   = t & 127;
    const int h    = td >> 4;
    const int d    = td & 15;

    __shared__ float heads[EMBED];
    __shared__ float mrg[2][EMBED][3];   // [half][td][{M,L,A}]

    float Mc[4], Lc[4], Ac[4];
    #pragma unroll
    for (int j = 0; j < 4; ++j) { Mc[j] = -INFINITY; Lc[j] = 0.f; Ac[j] = 0.f; }

    #pragma unroll
    for (int i = 0; i < 8; ++i) {
        #pragma unroll
        for (int j = 0; j < 4; ++j) {
            const int cc = half * 32 + j * 8 + i;
            const float* p = &part[((size_t)(b * NCHUNK + cc) * NHEADS + h) * PART_STRIDE];
            const float mc = p[0];
            const float lc = p[1];
            const float ac = p[2 + d];
            const float Mn = fmaxf(Mc[j], mc);
            const float eM = __expf(Mc[j] - Mn);
            const float ec = __expf(mc - Mn);
            Lc[j] = Lc[j] * eM + lc * ec;
            Ac[j] = Ac[j] * eM + ac * ec;
            Mc[j] = Mn;
        }
    }

    // Combine the 4 chains of this half.
    float M = fmaxf(fmaxf(Mc[0], Mc[1]), fmaxf(Mc[2], Mc[3]));
    float L = 0.f, A = 0.f;
    #pragma unroll
    for (int j = 0; j < 4; ++j) {
        const float e = __expf(Mc[j] - M);
        L += Lc[j] * e;
        A += Ac[j] * e;
    }
    mrg[half][td][0] = M;
    mrg[half][td][1] = L;
    mrg[half][td][2] = A;
    __syncthreads();

    // Combine the two halves (threads of half 0), normalize.
    if (half == 0) {
        const float M1 = mrg[1][td][0];
        const float L1 = mrg[1][td][1];
        const float A1 = mrg[1][td][2];
        const float Mt = fmaxf(M, M1);
        const float e0 = __expf(M - Mt);
        const float e1 = __expf(M1 - Mt);
        const float Lt = L * e0 + L1 * e1;
        const float At = A * e0 + A1 * e1;
        heads[td] = At / Lt;
    }
    __syncthreads();

    // W_out projection: 128 threads, coalesced column reads.
    if (t < EMBED) {
        float o = 0.f;
        #pragma unroll 8
        for (int dd = 0; dd < EMBED; ++dd)
            o += heads[dd] * Wout[dd * EMBED + t];
        out[b * EMBED + t] = o;
    }
}

extern "C" void kernel_launch(void* const* d_in, const int* in_sizes, int n_in,
                              void* d_out, int out_size, void* d_ws, size_t ws_size,
                              hipStream_t stream) {
    const float* q    = (const float*)d_in[0];
    const float* K    = (const float*)d_in[1];
    const float* V    = (const float*)d_in[2];
    const float* mask = (const float*)d_in[3];
    const float* Wout = (const float*)d_in[4];
    float* out  = (float*)d_out;
    float* part = (float*)d_ws;   // BATCH*NCHUNK*NHEADS*18 floats ≈ 1.18 MB

    attn_partial<<<BATCH * NCHUNK, 256, 0, stream>>>(q, K, V, mask, part);
    attn_finish<<<BATCH, 256, 0, stream>>>(part, Wout, out);
}